// Round 6
// baseline (125.452 us; speedup 1.0000x reference)
//
#include <hip/hip_runtime.h>
#include <math.h>

#define PI_F 3.14159265358979323846f
#define FLAG_MAGIC 0x9E3779B9u

typedef int v2i __attribute__((ext_vector_type(2)));

__device__ __forceinline__ float rcpf(float x) { return __builtin_amdgcn_rcpf(x); }
__device__ __forceinline__ void fswap(float2& p, float2& q) { float2 t = p; p = q; q = t; }

// ---------------------------------------------------------------------------
// QCNN: one wave per sample, 256-amp state in registers (4 float2/lane).
// qubit0 -> reg bit1, qubit1 -> reg bit0, qubit q in 2..7 -> lane bit (q-2).
// ---------------------------------------------------------------------------

template<int Q>
__device__ __forceinline__ float exq(float v) {
    if constexpr (Q == 2)        // lane^1: quad_perm [1,0,3,2]
        return __int_as_float(__builtin_amdgcn_update_dpp(0, __float_as_int(v), 0xB1, 0xF, 0xF, true));
    else if constexpr (Q == 3)   // lane^2: quad_perm [2,3,0,1]
        return __int_as_float(__builtin_amdgcn_update_dpp(0, __float_as_int(v), 0x4E, 0xF, 0xF, true));
    else if constexpr (Q == 4)   // lane^4
        return __int_as_float(__builtin_amdgcn_ds_swizzle(__float_as_int(v), 0x101F));
    else if constexpr (Q == 5)   // lane^8
        return __int_as_float(__builtin_amdgcn_ds_swizzle(__float_as_int(v), 0x201F));
    else if constexpr (Q == 6)   // lane^16
        return __int_as_float(__builtin_amdgcn_ds_swizzle(__float_as_int(v), 0x401F));
    else {                       // lane^32: permlane32_swap, pure VALU
        v2i r = __builtin_amdgcn_permlane32_swap(__float_as_int(v), __float_as_int(v), false, false);
        return __int_as_float((threadIdx.x & 32) ? r[0] : r[1]);
    }
}

template<int Q>
__device__ __forceinline__ void rzg(float2 a[4], float th, int lane) {
    float c = __cosf(0.5f * th), s = __sinf(0.5f * th);
    if constexpr (Q >= 2) {
        float se = ((lane >> (Q - 2)) & 1) ? s : -s;
        #pragma unroll
        for (int r = 0; r < 4; ++r) {
            float nx = c * a[r].x - se * a[r].y;
            float ny = c * a[r].y + se * a[r].x;
            a[r] = make_float2(nx, ny);
        }
    } else {
        #pragma unroll
        for (int r = 0; r < 4; ++r) {
            int bit = (Q == 0) ? (r >> 1) : (r & 1);
            float se = bit ? s : -s;
            float nx = c * a[r].x - se * a[r].y;
            float ny = c * a[r].y + se * a[r].x;
            a[r] = make_float2(nx, ny);
        }
    }
}

template<int Q>
__device__ __forceinline__ void ryg(float2 a[4], float th, int lane) {
    float c = __cosf(0.5f * th), s = __sinf(0.5f * th);
    if constexpr (Q >= 2) {
        float se = ((lane >> (Q - 2)) & 1) ? s : -s;
        #pragma unroll
        for (int r = 0; r < 4; ++r) {
            float ox = exq<Q>(a[r].x), oy = exq<Q>(a[r].y);
            a[r] = make_float2(c * a[r].x + se * ox, c * a[r].y + se * oy);
        }
    } else if constexpr (Q == 0) {
        #pragma unroll
        for (int r = 0; r < 2; ++r) {
            float2 lo = a[r], hi = a[r + 2];
            a[r]     = make_float2(c * lo.x - s * hi.x, c * lo.y - s * hi.y);
            a[r + 2] = make_float2(s * lo.x + c * hi.x, s * lo.y + c * hi.y);
        }
    } else {
        #pragma unroll
        for (int r = 0; r < 4; r += 2) {
            float2 lo = a[r], hi = a[r + 1];
            a[r]     = make_float2(c * lo.x - s * hi.x, c * lo.y - s * hi.y);
            a[r + 1] = make_float2(s * lo.x + c * hi.x, s * lo.y + c * hi.y);
        }
    }
}

template<int C, int T>
__device__ __forceinline__ void cxg(float2 a[4], int lane) {
    if constexpr (C >= 2) {
        bool cb = (lane >> (C - 2)) & 1;
        #pragma unroll
        for (int r = 0; r < 4; ++r) {
            float ox = exq<T>(a[r].x), oy = exq<T>(a[r].y);
            a[r].x = cb ? ox : a[r].x;
            a[r].y = cb ? oy : a[r].y;
        }
    } else if constexpr (C == 0 && T == 1) {
        fswap(a[2], a[3]);
    } else {
        fswap(a[1], a[3]);
    }
}

template<int Q>
__device__ __forceinline__ void featg(float2 a[4], float xq, int lane) {
    float phi = 2.0f * xq;
    float e1x = __cosf(phi), e1y = __sinf(phi);
    float e2x = e1x * e1x - e1y * e1y;
    float e2y = 2.0f * e1x * e1y;
    float2 u00 = make_float2(0.5f * (1.0f + e1x),  0.5f * e1y);
    float2 u01 = make_float2(0.5f * (1.0f - e1x), -0.5f * e1y);
    float2 u10 = make_float2(0.5f * (e1x - e2x), 0.5f * (e1y - e2y));
    float2 u11 = make_float2(0.5f * (e1x + e2x), 0.5f * (e1y + e2y));
    if constexpr (Q >= 2) {
        bool bset = (lane >> (Q - 2)) & 1;
        float csx = bset ? u11.x : u00.x, csy = bset ? u11.y : u00.y;
        float cox = bset ? u10.x : u01.x, coy = bset ? u10.y : u01.y;
        #pragma unroll
        for (int r = 0; r < 4; ++r) {
            float ox = exq<Q>(a[r].x), oy = exq<Q>(a[r].y);
            float nx = csx * a[r].x - csy * a[r].y + cox * ox - coy * oy;
            float ny = csx * a[r].y + csy * a[r].x + cox * oy + coy * ox;
            a[r] = make_float2(nx, ny);
        }
    } else {
        float2 l, h;
        #define APPL(LO, HI)                                                        \
            l = a[LO]; h = a[HI];                                                   \
            a[LO] = make_float2(u00.x*l.x - u00.y*l.y + u01.x*h.x - u01.y*h.y,      \
                                u00.x*l.y + u00.y*l.x + u01.x*h.y + u01.y*h.x);     \
            a[HI] = make_float2(u10.x*l.x - u10.y*l.y + u11.x*h.x - u11.y*h.y,      \
                                u10.x*l.y + u10.y*l.x + u11.x*h.y + u11.y*h.x);
        if constexpr (Q == 0) { APPL(0, 2) APPL(1, 3) }
        else                  { APPL(0, 1) APPL(2, 3) }
        #undef APPL
    }
}

template<int Q1, int Q2>
__device__ __forceinline__ void convg(float2 a[4], const float* __restrict__ p, int lane) {
    rzg<Q2>(a, -0.5f * PI_F, lane);
    cxg<Q2, Q1>(a, lane);
    rzg<Q1>(a, p[0], lane);
    ryg<Q2>(a, p[1], lane);
    cxg<Q1, Q2>(a, lane);
    ryg<Q2>(a, p[2], lane);
    cxg<Q2, Q1>(a, lane);
    rzg<Q1>(a, 0.5f * PI_F, lane);
}

template<int Q1, int Q2>
__device__ __forceinline__ void poolg(float2 a[4], const float* __restrict__ p, int lane) {
    rzg<Q2>(a, -0.5f * PI_F, lane);
    cxg<Q2, Q1>(a, lane);
    rzg<Q1>(a, p[0], lane);
    ryg<Q2>(a, p[1], lane);
    cxg<Q1, Q2>(a, lane);
    ryg<Q2>(a, p[2], lane);
}

template<int CTRL>
__device__ __forceinline__ float bq(float v) {   // quad_perm broadcast
    return __int_as_float(__builtin_amdgcn_update_dpp(0, __float_as_int(v), CTRL, 0xF, 0xF, true));
}

__device__ __forceinline__ float pick4(bool b0, bool b1, float a0, float a1, float a2, float a3) {
    float t01 = b0 ? a1 : a0;
    float t23 = b0 ? a3 : a2;
    return b1 ? t23 : t01;
}

// ---------------------------------------------------------------------------
// Fused kernel, PIPELINED handoff. One dispatch.
//   blocks 0..511 : QCNN producers; flag n = blockIdx*4 + wave, TIMESTEP-MAJOR
//                   (n = t*16 + b) so early blocks produce early timesteps.
//   block 512     : wave 0 = QLSTM consumer; stages 64-flag chunks (4
//                   timesteps x 16 batches) with 1-chunk lookahead.
// Handoff: flg[n] = (float_bits(qcnn_n) << 32) | (MAGIC ^ epoch); epoch at
// flg+2048, bumped by consumer each launch (replay/poison-safe; proven r1/r4).
//
// LESSON (r2/r3 forensics): DPP intrinsics must NEVER sit inside a
// lane-divergent select -- `qb0 ? dpp1(n1) : n0` can lower as a divergent
// branch, and update_dpp under partial exec reads 0 (bound_ctrl) from
// exec-disabled source lanes => silently-zero gates. The bq+pick4 path
// below executes all DPP unconditionally and selects afterwards.
//
// ROUND 5 infra-failed (container failed twice, no data); this is a verbatim
// resubmit. Single isolated change vs the passing r4 base: empty-asm "+v"
// pin of the 24 loop-invariant W/av scalars (r4 profile: VGPR_Count=28 =>
// compiler rematerializes ~24 loads inside the 128-step serial loop; the
// pin forces VGPR residency; loads hoisted before the spin so latency hides
// there). LSTM float expressions remain VERBATIM r4 (1e-7/step budget,
// ~4e4x amplification over 128 steps).
// ---------------------------------------------------------------------------

__device__ __forceinline__ void stage_chunk(int m, int lane, unsigned key,
                                            unsigned long long* __restrict__ flg,
                                            float* qsh) {
    int idx = m * 64 + lane;             // idx = t*16 + b
    unsigned long long v = __hip_atomic_load(&flg[idx], __ATOMIC_RELAXED, __HIP_MEMORY_SCOPE_AGENT);
    while ((unsigned)v != key) {
        __builtin_amdgcn_s_sleep(1);     // gentle spin: producers share the CU
        v = __hip_atomic_load(&flg[idx], __ATOMIC_RELAXED, __HIP_MEMORY_SCOPE_AGENT);
    }
    qsh[(idx & 15) * 132 + (idx >> 4)] = __uint_as_float((unsigned)(v >> 32));
}

__global__ __launch_bounds__(256, 1) void fused_kernel(
    const float* __restrict__ x,  const float* __restrict__ w,
    const float* __restrict__ thf, const float* __restrict__ thi,
    const float* __restrict__ thg, const float* __restrict__ tho,
    const float* __restrict__ Wf, const float* __restrict__ bf,
    const float* __restrict__ Wi, const float* __restrict__ bi,
    const float* __restrict__ Wg, const float* __restrict__ bg,
    const float* __restrict__ Wo, const float* __restrict__ bo,
    const float* __restrict__ Wh, const float* __restrict__ bh,
    float* __restrict__ out, unsigned long long* __restrict__ flg) {
    __shared__ __align__(16) float qsh[16 * 132];   // padded rows: conflict-free
    int lane = threadIdx.x & 63;
    int wave = threadIdx.x >> 6;
    unsigned* epoch = (unsigned*)(flg + 2048);

    if (blockIdx.x != 512) {
        // ---------------- QCNN producer ----------------
        unsigned key = FLAG_MAGIC ^ __hip_atomic_load(epoch, __ATOMIC_RELAXED, __HIP_MEMORY_SCOPE_AGENT);
        int n = blockIdx.x * 4 + wave;   // flag index, timestep-major
        int bb = n & 15, tt = n >> 4;    // batch, timestep
        int sidx = bb * 128 + tt;        // x/out layout index (batch-major)
        float2 a[4];
        a[0] = make_float2(lane == 0 ? 1.0f : 0.0f, 0.0f);
        a[1] = make_float2(0.0f, 0.0f);
        a[2] = make_float2(0.0f, 0.0f);
        a[3] = make_float2(0.0f, 0.0f);

        const float* xr = x + sidx * 8;
        featg<0>(a, xr[0], lane);
        featg<1>(a, xr[1], lane);
        featg<2>(a, xr[2], lane);
        featg<3>(a, xr[3], lane);
        featg<4>(a, xr[4], lane);
        featg<5>(a, xr[5], lane);
        featg<6>(a, xr[6], lane);
        featg<7>(a, xr[7], lane);

        convg<0,1>(a, w + 0,  lane);
        convg<2,3>(a, w + 3,  lane);
        convg<4,5>(a, w + 6,  lane);
        convg<6,7>(a, w + 9,  lane);
        poolg<0,1>(a, w + 12, lane);
        poolg<2,3>(a, w + 15, lane);
        poolg<4,5>(a, w + 18, lane);
        poolg<6,7>(a, w + 21, lane);
        convg<0,1>(a, w + 24, lane);
        convg<2,3>(a, w + 27, lane);
        poolg<0,1>(a, w + 30, lane);
        poolg<2,3>(a, w + 33, lane);
        convg<0,1>(a, w + 36, lane);
        poolg<0,1>(a, w + 39, lane);

        // <Z_q7>: q7 = lane bit5
        float ssum = 0.f;
        #pragma unroll
        for (int r = 0; r < 4; ++r)
            ssum += a[r].x * a[r].x + a[r].y * a[r].y;
        ssum = (lane & 32) ? -ssum : ssum;
        ssum += exq<2>(ssum);
        ssum += exq<3>(ssum);
        ssum += exq<4>(ssum);
        ssum += exq<5>(ssum);
        ssum += exq<6>(ssum);
        {
            v2i rr = __builtin_amdgcn_permlane32_swap(__float_as_int(ssum), __float_as_int(ssum), false, false);
            ssum = __int_as_float((threadIdx.x & 32) ? rr[0] : rr[1]) +
                   __int_as_float((threadIdx.x & 32) ? rr[1] : rr[0]);
        }
        if (lane == 0) {
            out[sidx] = ssum;
            unsigned long long pk = ((unsigned long long)__float_as_uint(ssum) << 32)
                                  | (unsigned long long)key;
            __hip_atomic_store(&flg[n], pk, __ATOMIC_RELAXED, __HIP_MEMORY_SCOPE_AGENT);
        }
        return;
    }

    // ---------------- QLSTM consumer (block 512, wave 0 only) ----------------
    if (wave != 0) return;
    unsigned key = FLAG_MAGIC ^ __hip_atomic_load(epoch, __ATOMIC_RELAXED, __HIP_MEMORY_SCOPE_AGENT);

    int b = lane >> 2, q = lane & 3;
    bool qb0 = q & 1, qb1 = q & 2;
    const float* Wp = (q == 0) ? Wf : (q == 1) ? Wi : (q == 2) ? Wg : Wo;
    const float* bp = (q == 0) ? bf : (q == 1) ? bi : (q == 2) ? bg : bo;
    const float* tp = (q == 0) ? thf : (q == 1) ? thi : (q == 2) ? thg : tho;

    // Load + PIN loop-invariant scalars before the spin (latency hides under
    // the wait; empty asm forces VGPR residency -- the compiler cannot
    // rematerialize these loads inside the 128-step loop).
    float W0_ = Wp[0],  W1_ = Wp[1],  W2_ = Wp[2],  W3_ = Wp[3],  W4_ = Wp[4];
    float W5_ = Wp[5],  W6_ = Wp[6],  W7_ = Wp[7],  W8_ = Wp[8],  W9_ = Wp[9];
    float W10_ = Wp[10], W11_ = Wp[11], W12_ = Wp[12], W13_ = Wp[13], W14_ = Wp[14];
    float W15_ = Wp[15], W16_ = Wp[16], W17_ = Wp[17], W18_ = Wp[18], W19_ = Wp[19];
    float av0 = bp[0] + tp[0], av1 = bp[1] + tp[1];
    float av2 = bp[2] + tp[2], av3 = bp[3] + tp[3];
    float wh0 = Wh[0], wh1 = Wh[1], wh2 = Wh[2], wh3 = Wh[3], bh0 = bh[0];
    asm volatile("" :
        "+v"(W0_), "+v"(W1_), "+v"(W2_), "+v"(W3_), "+v"(W4_),
        "+v"(W5_), "+v"(W6_), "+v"(W7_), "+v"(W8_), "+v"(W9_),
        "+v"(W10_), "+v"(W11_), "+v"(W12_), "+v"(W13_), "+v"(W14_),
        "+v"(W15_), "+v"(W16_), "+v"(W17_), "+v"(W18_), "+v"(W19_),
        "+v"(av0), "+v"(av1), "+v"(av2), "+v"(av3));

    stage_chunk(0, lane, key, flg, qsh);      // timesteps 0..3
    __builtin_amdgcn_wave_barrier();

    // gate-q nonlinearity constants (tanh for q==2, sigmoid otherwise)
    float nA = (q == 2) ? 1.0f : 0.0f;
    float nB = (q == 2) ? -2.0f : 1.0f;
    float nK = (q == 2) ? 2.0f : -1.0f;

    float c = 0.f;
    float h0 = 0.f, h1 = 0.f, h2 = 0.f, h3 = 0.f;
    const float* qrow = &qsh[b * 132];

    for (int j = 0; j < 32; ++j) {
        if (j < 31) stage_chunk(j + 1, lane, key, flg, qsh);  // lookahead
        __builtin_amdgcn_wave_barrier();
        // one ds_read_b128: this chunk's 4 x-values (16B-aligned: 132*4B*b and
        // 16B*j are both multiples of 16) -- off the per-step critical path
        float4 xq4 = *(const float4*)&qrow[4 * j];
        #pragma unroll
        for (int k = 0; k < 4; ++k) {
            float xv = (k == 0) ? xq4.x : (k == 1) ? xq4.y : (k == 2) ? xq4.z : xq4.w;
            float vA = av0 + W0_*xv  + W1_*h0  + W2_*h1  + W3_*h2  + W4_*h3;
            float vB = av1 + W5_*xv  + W6_*h0  + W7_*h1  + W8_*h2  + W9_*h3;
            float vC = av2 + W10_*xv + W11_*h0 + W12_*h1 + W13_*h2 + W14_*h3;
            float vD = av3 + W15_*xv + W16_*h0 + W17_*h1 + W18_*h2 + W19_*h3;
            float cA = __cosf(vA), cB = __cosf(vB), cC = __cosf(vC), cD = __cosf(vD);
            float r1 = cA * cB, r2 = r1 * cC, r3 = r2 * cD, r0 = cB * (cC * cD);
            // unified nonlinearity (verbatim passing-r4: exp-based)
            float E0 = __expf(nK * r0), E1 = __expf(nK * r1);
            float E2 = __expf(nK * r2), E3 = __expf(nK * r3);
            float n0 = nA + nB * rcpf(E0 + 1.0f);
            float n1 = nA + nB * rcpf(E1 + 1.0f);
            float n2 = nA + nB * rcpf(E2 + 1.0f);
            float n3 = nA + nB * rcpf(E3 + 1.0f);
            // broadcast all 16 gate x row values across the quad (DPP executed
            // unconditionally; selection via cndmask AFTER -- see lesson above)
            float F0 = bq<0x00>(n0), F1 = bq<0x00>(n1), F2 = bq<0x00>(n2), F3 = bq<0x00>(n3);
            float I0 = bq<0x55>(n0), I1 = bq<0x55>(n1), I2 = bq<0x55>(n2), I3 = bq<0x55>(n3);
            float G0 = bq<0xAA>(n0), G1 = bq<0xAA>(n1), G2 = bq<0xAA>(n2), G3 = bq<0xAA>(n3);
            float O0 = bq<0xFF>(n0), O1 = bq<0xFF>(n1), O2 = bq<0xFF>(n2), O3 = bq<0xFF>(n3);
            float F = pick4(qb0, qb1, F0, F1, F2, F3);
            float I = pick4(qb0, qb1, I0, I1, I2, I3);
            float G = pick4(qb0, qb1, G0, G1, G2, G3);
            float O = pick4(qb0, qb1, O0, O1, O2, O3);
            c = F * c + I * G;
            float Ec = __expf(2.0f * c);
            float tau = 1.0f - 2.0f * rcpf(Ec + 1.0f);
            float hq = O * tau;
            h0 = bq<0x00>(hq);
            h1 = bq<0x55>(hq);
            h2 = bq<0xAA>(hq);
            h3 = bq<0xFF>(hq);
        }
    }

    if (q == 0)
        out[2048 + b] = bh0 + wh0*h0 + wh1*h1 + wh2*h2 + wh3*h3;

    if (lane == 0)
        __hip_atomic_fetch_add(epoch, 1u, __ATOMIC_RELAXED, __HIP_MEMORY_SCOPE_AGENT);
}

extern "C" void kernel_launch(void* const* d_in, const int* in_sizes, int n_in,
                              void* d_out, int out_size, void* d_ws, size_t ws_size,
                              hipStream_t stream) {
    fused_kernel<<<513, 256, 0, stream>>>(
        (const float*)d_in[0],  (const float*)d_in[1],
        (const float*)d_in[2],  (const float*)d_in[3],
        (const float*)d_in[4],  (const float*)d_in[5],
        (const float*)d_in[6],  (const float*)d_in[7],
        (const float*)d_in[8],  (const float*)d_in[9],
        (const float*)d_in[10], (const float*)d_in[11],
        (const float*)d_in[12], (const float*)d_in[13],
        (const float*)d_in[14], (const float*)d_in[15],
        (float*)d_out, (unsigned long long*)d_ws);
}

// Round 7
// 118.817 us; speedup vs baseline: 1.0558x; 1.0558x over previous
//
#include <hip/hip_runtime.h>
#include <math.h>

#define PI_F 3.14159265358979323846f
#define FLAG_MAGIC 0x9E3779B9u

typedef int v2i __attribute__((ext_vector_type(2)));

__device__ __forceinline__ float rcpf(float x) { return __builtin_amdgcn_rcpf(x); }
__device__ __forceinline__ void fswap(float2& p, float2& q) { float2 t = p; p = q; q = t; }

// ---------------------------------------------------------------------------
// QCNN: one wave per sample, 256-amp state in registers (4 float2/lane).
// qubit0 -> reg bit1, qubit1 -> reg bit0, qubit q in 2..7 -> lane bit (q-2).
// (UNCHANGED from the passing r4/r6 kernel.)
// ---------------------------------------------------------------------------

template<int Q>
__device__ __forceinline__ float exq(float v) {
    if constexpr (Q == 2)        // lane^1: quad_perm [1,0,3,2]
        return __int_as_float(__builtin_amdgcn_update_dpp(0, __float_as_int(v), 0xB1, 0xF, 0xF, true));
    else if constexpr (Q == 3)   // lane^2: quad_perm [2,3,0,1]
        return __int_as_float(__builtin_amdgcn_update_dpp(0, __float_as_int(v), 0x4E, 0xF, 0xF, true));
    else if constexpr (Q == 4)   // lane^4
        return __int_as_float(__builtin_amdgcn_ds_swizzle(__float_as_int(v), 0x101F));
    else if constexpr (Q == 5)   // lane^8
        return __int_as_float(__builtin_amdgcn_ds_swizzle(__float_as_int(v), 0x201F));
    else if constexpr (Q == 6)   // lane^16
        return __int_as_float(__builtin_amdgcn_ds_swizzle(__float_as_int(v), 0x401F));
    else {                       // lane^32: permlane32_swap, pure VALU
        v2i r = __builtin_amdgcn_permlane32_swap(__float_as_int(v), __float_as_int(v), false, false);
        return __int_as_float((threadIdx.x & 32) ? r[0] : r[1]);
    }
}

template<int Q>
__device__ __forceinline__ void rzg(float2 a[4], float th, int lane) {
    float c = __cosf(0.5f * th), s = __sinf(0.5f * th);
    if constexpr (Q >= 2) {
        float se = ((lane >> (Q - 2)) & 1) ? s : -s;
        #pragma unroll
        for (int r = 0; r < 4; ++r) {
            float nx = c * a[r].x - se * a[r].y;
            float ny = c * a[r].y + se * a[r].x;
            a[r] = make_float2(nx, ny);
        }
    } else {
        #pragma unroll
        for (int r = 0; r < 4; ++r) {
            int bit = (Q == 0) ? (r >> 1) : (r & 1);
            float se = bit ? s : -s;
            float nx = c * a[r].x - se * a[r].y;
            float ny = c * a[r].y + se * a[r].x;
            a[r] = make_float2(nx, ny);
        }
    }
}

template<int Q>
__device__ __forceinline__ void ryg(float2 a[4], float th, int lane) {
    float c = __cosf(0.5f * th), s = __sinf(0.5f * th);
    if constexpr (Q >= 2) {
        float se = ((lane >> (Q - 2)) & 1) ? s : -s;
        #pragma unroll
        for (int r = 0; r < 4; ++r) {
            float ox = exq<Q>(a[r].x), oy = exq<Q>(a[r].y);
            a[r] = make_float2(c * a[r].x + se * ox, c * a[r].y + se * oy);
        }
    } else if constexpr (Q == 0) {
        #pragma unroll
        for (int r = 0; r < 2; ++r) {
            float2 lo = a[r], hi = a[r + 2];
            a[r]     = make_float2(c * lo.x - s * hi.x, c * lo.y - s * hi.y);
            a[r + 2] = make_float2(s * lo.x + c * hi.x, s * lo.y + c * hi.y);
        }
    } else {
        #pragma unroll
        for (int r = 0; r < 4; r += 2) {
            float2 lo = a[r], hi = a[r + 1];
            a[r]     = make_float2(c * lo.x - s * hi.x, c * lo.y - s * hi.y);
            a[r + 1] = make_float2(s * lo.x + c * hi.x, s * lo.y + c * hi.y);
        }
    }
}

template<int C, int T>
__device__ __forceinline__ void cxg(float2 a[4], int lane) {
    if constexpr (C >= 2) {
        bool cb = (lane >> (C - 2)) & 1;
        #pragma unroll
        for (int r = 0; r < 4; ++r) {
            float ox = exq<T>(a[r].x), oy = exq<T>(a[r].y);
            a[r].x = cb ? ox : a[r].x;
            a[r].y = cb ? oy : a[r].y;
        }
    } else if constexpr (C == 0 && T == 1) {
        fswap(a[2], a[3]);
    } else {
        fswap(a[1], a[3]);
    }
}

template<int Q>
__device__ __forceinline__ void featg(float2 a[4], float xq, int lane) {
    float phi = 2.0f * xq;
    float e1x = __cosf(phi), e1y = __sinf(phi);
    float e2x = e1x * e1x - e1y * e1y;
    float e2y = 2.0f * e1x * e1y;
    float2 u00 = make_float2(0.5f * (1.0f + e1x),  0.5f * e1y);
    float2 u01 = make_float2(0.5f * (1.0f - e1x), -0.5f * e1y);
    float2 u10 = make_float2(0.5f * (e1x - e2x), 0.5f * (e1y - e2y));
    float2 u11 = make_float2(0.5f * (e1x + e2x), 0.5f * (e1y + e2y));
    if constexpr (Q >= 2) {
        bool bset = (lane >> (Q - 2)) & 1;
        float csx = bset ? u11.x : u00.x, csy = bset ? u11.y : u00.y;
        float cox = bset ? u10.x : u01.x, coy = bset ? u10.y : u01.y;
        #pragma unroll
        for (int r = 0; r < 4; ++r) {
            float ox = exq<Q>(a[r].x), oy = exq<Q>(a[r].y);
            float nx = csx * a[r].x - csy * a[r].y + cox * ox - coy * oy;
            float ny = csx * a[r].y + csy * a[r].x + cox * oy + coy * ox;
            a[r] = make_float2(nx, ny);
        }
    } else {
        float2 l, h;
        #define APPL(LO, HI)                                                        \
            l = a[LO]; h = a[HI];                                                   \
            a[LO] = make_float2(u00.x*l.x - u00.y*l.y + u01.x*h.x - u01.y*h.y,      \
                                u00.x*l.y + u00.y*l.x + u01.x*h.y + u01.y*h.x);     \
            a[HI] = make_float2(u10.x*l.x - u10.y*l.y + u11.x*h.x - u11.y*h.y,      \
                                u10.x*l.y + u10.y*l.x + u11.x*h.y + u11.y*h.x);
        if constexpr (Q == 0) { APPL(0, 2) APPL(1, 3) }
        else                  { APPL(0, 1) APPL(2, 3) }
        #undef APPL
    }
}

template<int Q1, int Q2>
__device__ __forceinline__ void convg(float2 a[4], const float* __restrict__ p, int lane) {
    rzg<Q2>(a, -0.5f * PI_F, lane);
    cxg<Q2, Q1>(a, lane);
    rzg<Q1>(a, p[0], lane);
    ryg<Q2>(a, p[1], lane);
    cxg<Q1, Q2>(a, lane);
    ryg<Q2>(a, p[2], lane);
    cxg<Q2, Q1>(a, lane);
    rzg<Q1>(a, 0.5f * PI_F, lane);
}

template<int Q1, int Q2>
__device__ __forceinline__ void poolg(float2 a[4], const float* __restrict__ p, int lane) {
    rzg<Q2>(a, -0.5f * PI_F, lane);
    cxg<Q2, Q1>(a, lane);
    rzg<Q1>(a, p[0], lane);
    ryg<Q2>(a, p[1], lane);
    cxg<Q1, Q2>(a, lane);
    ryg<Q2>(a, p[2], lane);
}

template<int CTRL>
__device__ __forceinline__ float bq(float v) {   // quad_perm broadcast
    return __int_as_float(__builtin_amdgcn_update_dpp(0, __float_as_int(v), CTRL, 0xF, 0xF, true));
}

// ds_swizzle BitMode gate-gather: src_lane = (lane & 0x13) | (G<<2).
// Pattern-explicit (no shift-direction ambiguity); lane bits: j=[1:0],
// gate=[3:2], batch=[4] within each 32-lane half (batch bit 5 = half).
template<int OFF>
__device__ __forceinline__ float swz(float v) {
    return __int_as_float(__builtin_amdgcn_ds_swizzle(__float_as_int(v), OFF));
}

// ---------------------------------------------------------------------------
// Fused kernel, PIPELINED handoff. One dispatch.
//   blocks 0..511 : QCNN producers; flag n = blockIdx*4 + wave, TIMESTEP-MAJOR
//                   (n = t*16 + b) so early blocks produce early timesteps.
//   block 512     : QLSTM consumer, ALL 4 WAVES. Wave w owns batches 4w..4w+3
//                   end-to-end (its own flags, LDS region, recurrence) -->
//                   zero cross-wave sync. Lane = (b,g,j): j=row (quad bits),
//                   g=gate (bits[3:2]), b=batch (bits[5:4] + wave).
// Per-lane live set: 5 W + 1 av + h0..h3 + c + temps ~= 22 regs -- fits the
// allocator's 28-reg choice (r4/r6 profiles) WITHOUT per-step spill/remat.
// (r6 falsified the asm-pin fix: VGPR stayed 28, dur unchanged -> allocator
// caps at producer pressure and spills the consumer; so shrink the consumer.)
//
// Numerics: every float expression is association-matched to the passing r4
// code (1e-7/step budget, ~4e4x amplification): dot left-assoc, products
// r0=cB*(cC*cD), r1=cA*cB, r2=r1*cC, r3=r2*cD, exp-based nonlinearities.
// Cross-lane: quad bq DPP (r4-proven) + explicit-pattern ds_swizzle; ALL
// executed unconditionally (r2/r3 lesson: DPP never under divergent select).
// ---------------------------------------------------------------------------

__global__ __launch_bounds__(256, 1) void fused_kernel(
    const float* __restrict__ x,  const float* __restrict__ w,
    const float* __restrict__ thf, const float* __restrict__ thi,
    const float* __restrict__ thg, const float* __restrict__ tho,
    const float* __restrict__ Wf, const float* __restrict__ bf,
    const float* __restrict__ Wi, const float* __restrict__ bi,
    const float* __restrict__ Wg, const float* __restrict__ bg,
    const float* __restrict__ Wo, const float* __restrict__ bo,
    const float* __restrict__ Wh, const float* __restrict__ bh,
    float* __restrict__ out, unsigned long long* __restrict__ flg) {
    __shared__ __align__(16) float qsh[4][4 * 132];   // per-wave [4 batches][132]
    int lane = threadIdx.x & 63;
    int wv = threadIdx.x >> 6;
    unsigned* epoch = (unsigned*)(flg + 2048);

    if (blockIdx.x != 512) {
        // ---------------- QCNN producer (UNCHANGED) ----------------
        unsigned key = FLAG_MAGIC ^ __hip_atomic_load(epoch, __ATOMIC_RELAXED, __HIP_MEMORY_SCOPE_AGENT);
        int n = blockIdx.x * 4 + wv;     // flag index, timestep-major
        int bb = n & 15, tt = n >> 4;    // batch, timestep
        int sidx = bb * 128 + tt;        // x/out layout index (batch-major)
        float2 a[4];
        a[0] = make_float2(lane == 0 ? 1.0f : 0.0f, 0.0f);
        a[1] = make_float2(0.0f, 0.0f);
        a[2] = make_float2(0.0f, 0.0f);
        a[3] = make_float2(0.0f, 0.0f);

        const float* xr = x + sidx * 8;
        featg<0>(a, xr[0], lane);
        featg<1>(a, xr[1], lane);
        featg<2>(a, xr[2], lane);
        featg<3>(a, xr[3], lane);
        featg<4>(a, xr[4], lane);
        featg<5>(a, xr[5], lane);
        featg<6>(a, xr[6], lane);
        featg<7>(a, xr[7], lane);

        convg<0,1>(a, w + 0,  lane);
        convg<2,3>(a, w + 3,  lane);
        convg<4,5>(a, w + 6,  lane);
        convg<6,7>(a, w + 9,  lane);
        poolg<0,1>(a, w + 12, lane);
        poolg<2,3>(a, w + 15, lane);
        poolg<4,5>(a, w + 18, lane);
        poolg<6,7>(a, w + 21, lane);
        convg<0,1>(a, w + 24, lane);
        convg<2,3>(a, w + 27, lane);
        poolg<0,1>(a, w + 30, lane);
        poolg<2,3>(a, w + 33, lane);
        convg<0,1>(a, w + 36, lane);
        poolg<0,1>(a, w + 39, lane);

        float ssum = 0.f;
        #pragma unroll
        for (int r = 0; r < 4; ++r)
            ssum += a[r].x * a[r].x + a[r].y * a[r].y;
        ssum = (lane & 32) ? -ssum : ssum;
        ssum += exq<2>(ssum);
        ssum += exq<3>(ssum);
        ssum += exq<4>(ssum);
        ssum += exq<5>(ssum);
        ssum += exq<6>(ssum);
        {
            v2i rr = __builtin_amdgcn_permlane32_swap(__float_as_int(ssum), __float_as_int(ssum), false, false);
            ssum = __int_as_float((threadIdx.x & 32) ? rr[0] : rr[1]) +
                   __int_as_float((threadIdx.x & 32) ? rr[1] : rr[0]);
        }
        if (lane == 0) {
            out[sidx] = ssum;
            unsigned long long pk = ((unsigned long long)__float_as_uint(ssum) << 32)
                                  | (unsigned long long)key;
            __hip_atomic_store(&flg[n], pk, __ATOMIC_RELAXED, __HIP_MEMORY_SCOPE_AGENT);
        }
        return;
    }

    // ---------------- QLSTM consumer: 4 independent waves ----------------
    unsigned key = FLAG_MAGIC ^ __hip_atomic_load(epoch, __ATOMIC_RELAXED, __HIP_MEMORY_SCOPE_AGENT);

    int j4 = lane & 3;           // row (quad index)
    int g  = (lane >> 2) & 3;    // gate: 0=F 1=I 2=G 3=O
    int bl = (lane >> 4) & 3;    // batch within wave
    float* xrow = &qsh[wv][0];

    const float* Wp = (g == 0) ? Wf : (g == 1) ? Wi : (g == 2) ? Wg : Wo;
    const float* bp = (g == 0) ? bf : (g == 1) ? bi : (g == 2) ? bg : bo;
    const float* tp = (g == 0) ? thf : (g == 1) ? thi : (g == 2) ? thg : tho;

    // 6 loop-invariants per lane (row j4 of gate g's 4x5 matrix)
    float w0 = Wp[j4 * 5 + 0], w1 = Wp[j4 * 5 + 1], w2 = Wp[j4 * 5 + 2];
    float w3 = Wp[j4 * 5 + 3], w4 = Wp[j4 * 5 + 4];
    float av = bp[j4] + tp[j4];
    float nA = (g == 2) ? 1.0f : 0.0f;
    float nB = (g == 2) ? -2.0f : 1.0f;
    float nK = (g == 2) ? 2.0f : -1.0f;

    // stage chunk m: 16 lanes fetch flags (4 timesteps x this wave's 4 batches)
    #define STAGE16(m)                                                              \
        if (lane < 16) {                                                            \
            int fidx = (4 * (m) + (lane >> 2)) * 16 + (wv * 4 + (lane & 3));        \
            unsigned long long v = __hip_atomic_load(&flg[fidx], __ATOMIC_RELAXED,  \
                                                     __HIP_MEMORY_SCOPE_AGENT);     \
            while ((unsigned)v != key) {                                            \
                __builtin_amdgcn_s_sleep(1);                                        \
                v = __hip_atomic_load(&flg[fidx], __ATOMIC_RELAXED,                 \
                                      __HIP_MEMORY_SCOPE_AGENT);                    \
            }                                                                       \
            xrow[(lane & 3) * 132 + 4 * (m) + (lane >> 2)] =                        \
                __uint_as_float((unsigned)(v >> 32));                               \
        }

    STAGE16(0)
    __builtin_amdgcn_wave_barrier();

    float c = 0.f;
    float h0 = 0.f, h1 = 0.f, h2 = 0.f, h3 = 0.f;

    for (int j = 0; j < 32; ++j) {
        if (j < 31) STAGE16(j + 1)          // lookahead (reconverges before barrier)
        __builtin_amdgcn_wave_barrier();
        float4 xq4 = *(const float4*)&xrow[bl * 132 + 4 * j];   // 16B-aligned
        #pragma unroll
        for (int k = 0; k < 4; ++k) {
            float xv = (k == 0) ? xq4.x : (k == 1) ? xq4.y : (k == 2) ? xq4.z : xq4.w;
            // own angle (row j4 of gate g), r4-identical association
            float v = av + w0 * xv + w1 * h0 + w2 * h1 + w3 * h2 + w4 * h3;
            float co = __cosf(v);
            // quad broadcast of the 4 cosines (j4 is the quad index)
            float b0 = bq<0x00>(co), b1 = bq<0x55>(co), b2 = bq<0xAA>(co), b3 = bq<0xFF>(co);
            // per-lane row product, association-matched to r4:
            //   r0=cB*(cC*cD), r1=cA*cB, r2=r1*cC, r3=r2*cD
            float p01 = b0 * b1;
            float q23 = b2 * b3;
            float a0  = b1 * q23;                 // r0
            float s   = (j4 == 1) ? 1.0f : b2;
            float t   = p01 * s;                  // r1 (x1.0 exact) or r2
            float t3  = t * b3;                   // r3 when j4==3 (=(r1*cC)*cD)
            float r   = (j4 == 0) ? a0 : ((j4 == 3) ? t3 : t);
            // unified nonlinearity (verbatim r4: exp-based; tanh iff g==2)
            float E = __expf(nK * r);
            float n = nA + nB * rcpf(E + 1.0f);
            // gate 4x4 transpose: explicit-pattern ds_swizzle, unconditional
            float F = swz<0x013>(n);   // n(gate0, row j4)
            float I = swz<0x093>(n);   // n(gate1, row j4)
            float G = swz<0x113>(n);   // n(gate2, row j4)
            float O = swz<0x193>(n);   // n(gate3, row j4)
            c = F * c + I * G;
            float Ec = __expf(2.0f * c);
            float tau = 1.0f - 2.0f * rcpf(Ec + 1.0f);
            float hq = O * tau;                   // identical across the 4 g-lanes
            h0 = bq<0x00>(hq);
            h1 = bq<0x55>(hq);
            h2 = bq<0xAA>(hq);
            h3 = bq<0xFF>(hq);
        }
    }
    #undef STAGE16

    if ((lane & 15) == 0)                       // one lane per batch
        out[2048 + wv * 4 + bl] = bh[0] + Wh[0]*h0 + Wh[1]*h1 + Wh[2]*h2 + Wh[3]*h3;

    // epoch bump: safe -- every producer has read epoch before its flags were
    // written, and all flags precede any consumer wave finishing.
    if (threadIdx.x == 0)
        __hip_atomic_fetch_add(epoch, 1u, __ATOMIC_RELAXED, __HIP_MEMORY_SCOPE_AGENT);
}

extern "C" void kernel_launch(void* const* d_in, const int* in_sizes, int n_in,
                              void* d_out, int out_size, void* d_ws, size_t ws_size,
                              hipStream_t stream) {
    fused_kernel<<<513, 256, 0, stream>>>(
        (const float*)d_in[0],  (const float*)d_in[1],
        (const float*)d_in[2],  (const float*)d_in[3],
        (const float*)d_in[4],  (const float*)d_in[5],
        (const float*)d_in[6],  (const float*)d_in[7],
        (const float*)d_in[8],  (const float*)d_in[9],
        (const float*)d_in[10], (const float*)d_in[11],
        (const float*)d_in[12], (const float*)d_in[13],
        (const float*)d_in[14], (const float*)d_in[15],
        (float*)d_out, (unsigned long long*)d_ws);
}